// Round 7
// baseline (302.076 us; speedup 1.0000x reference)
//
#include <hip/hip_runtime.h>
#include <stdint.h>

typedef unsigned long long u64;
typedef __attribute__((ext_vector_type(8))) short bf16x8;
typedef __attribute__((ext_vector_type(4))) float f32x4;
typedef __attribute__((ext_vector_type(4))) unsigned u32x4;

#define BATCH 512
#define FEAT 256
#define ENC 2048
#define HID 4096
#define CLS 1000
#define KTOT 12288      // 3 * 4096
#define KSPLIT 768

// ws offsets
#define OFF_ENC2   0
#define OFF_ACT2   131072
#define OFF_TABLE  917504
#define OFF_SGN    1703936      // {negbits,validbits} u32 pairs per neuron
#define OFF_CNT    1802240      // 16 padded counters (128B apart) = 2KB
#define OFF_WT     2097152

// ---------- fp32 -> bf16 RNE ----------
static __device__ inline unsigned short f2bf(float f) {
    unsigned u = __float_as_uint(f);
    return (unsigned short)((u + 0x7FFFu + ((u >> 16) & 1u)) >> 16);
}

// ---------- async global->LDS, 16B/lane ----------
static __device__ inline void gld16(const void* g, void* s) {
    __builtin_amdgcn_global_load_lds((const __attribute__((address_space(1))) void*)g,
                                     (__attribute__((address_space(3))) void*)s, 16, 0, 0);
}

// ================= kernel 1: fused prep = encode+zero | scan | twt =================
// blocks [0,512): encode + zero out + zero sync   [512,3584): scan   [3584,6656): twt
__global__ void __launch_bounds__(256)
k_prep(const float* __restrict__ x, u64* __restrict__ enc2,
       const float* __restrict__ W0, const float* __restrict__ W1,
       const float* __restrict__ W2,
       uint16_t* __restrict__ table, unsigned* __restrict__ bits,
       const float* __restrict__ out_w, short* __restrict__ wt,
       float* __restrict__ out, int* __restrict__ sync) {
    __shared__ short tile[64 * 68];
    int bid = blockIdx.x;
    int t = threadIdx.x;
    int lane = t & 63;
    int wv = t >> 6;

    if (bid < 512) {
        if (bid == 0) { sync[t] = 0; sync[t + 256] = 0; }   // zero 512 ints (padded ctrs)
        // zero out (512*256 float4 slots cover the 128000 needed)
        int oidx = bid * 256 + t;
        if (oidx < (BATCH * CLS) / 4) {
            f32x4 z = {0.f, 0.f, 0.f, 0.f};
            *(f32x4*)&out[(size_t)oidx * 4] = z;
        }
        int wid = bid * 4 + wv;
        int f = wid >> 3, bg = wid & 7;
        float v = x[(size_t)(bg * 64 + lane) * FEAT + f];
        v = fminf(fmaxf(v, 0.0f), 1.0f);
        int lev = (int)rintf(v * 255.0f);                // RNE == jnp.round
        unsigned gray = (unsigned)(lev ^ (lev >> 1));
        u64 w = 0;
        #pragma unroll
        for (int bit = 0; bit < 8; ++bit) {
            u64 m = __ballot((gray >> bit) & 1u);
            if (lane == bit) w = m;
        }
        if (lane < 8) enc2[(size_t)bg * ENC + f * 8 + lane] = w;
        return;
    }
    if (bid < 3584) {
        // ---- scan: 1 wave = 1 weight row; ballot+prefix slot assignment (no atomics) --
        int row = (bid - 512) * 4 + wv;
        const float* Wr; int npass;
        if (row < HID)          { Wr = W0 + (size_t)row * ENC;             npass = 1; }
        else if (row < 2 * HID) { Wr = W1 + (size_t)(row - HID) * HID;     npass = 2; }
        else                    { Wr = W2 + (size_t)(row - 2 * HID) * HID; npass = 2; }
        uint16_t* te = table + (size_t)row * 32;
        unsigned cnt = 0, mynegs = 0;
        u64 ltmask = (1ull << lane) - 1ull;
        for (int p = 0; p < npass; ++p) {
            const u32x4* p4 = (const u32x4*)Wr + p * 512 + lane;
            u32x4 v[8];
            #pragma unroll
            for (int j = 0; j < 8; ++j) v[j] = __builtin_nontemporal_load(p4 + j * 64);
            #pragma unroll
            for (int j = 0; j < 8; ++j) {
                int col0 = (p * 8 + j) * 256 + lane * 4;
                unsigned aa[4] = {v[j].x, v[j].y, v[j].z, v[j].w};
                #pragma unroll
                for (int c = 0; c < 4; ++c) {
                    unsigned a = aa[c];
                    u64 m = __ballot(a != 0u);
                    if (a) {
                        int slot = (int)cnt + (int)__popcll(m & ltmask);
                        te[slot] = (uint16_t)(col0 + c);
                        if (a >> 31) mynegs |= 1u << slot;
                    }
                    cnt += (unsigned)__popcll(m);
                }
            }
        }
        // wave OR-reduce of negbits
        #pragma unroll
        for (int off = 32; off; off >>= 1) mynegs |= __shfl_xor(mynegs, off);
        // tail-pad unused slots (disjoint addresses from the scatter -> no ordering hazard)
        if (lane >= (int)cnt && lane < 32) te[lane] = 0;
        if (lane == 0) {
            uint2 pr;
            pr.x = mynegs;
            pr.y = (cnt >= 32) ? 0xFFFFFFFFu : ((1u << cnt) - 1u);
            *(uint2*)(bits + (size_t)row * 2) = pr;
        }
        return;
    }
    {
        // ---- twt: transpose+convert out_w -> wt bf16 (swizzled) ----
        int b2 = bid - 3584;
        int kt = b2 % 192, ct = b2 / 192;
        int k0 = kt * 64, c0 = ct * 64;
        {
            int rrow = t >> 4, c4 = t & 15;
            int c = c0 + c4 * 4;
            #pragma unroll
            for (int rd = 0; rd < 4; ++rd) {
                int kl = rd * 16 + rrow;
                f32x4 vv;
                if (c < CLS)
                    vv = __builtin_nontemporal_load(
                        (const f32x4*)&out_w[(size_t)(k0 + kl) * CLS + c]);
                else { vv.x = 0.0f; vv.y = 0.0f; vv.z = 0.0f; vv.w = 0.0f; }
                short* d = &tile[kl * 68 + c4 * 4];
                d[0] = (short)f2bf(vv.x); d[1] = (short)f2bf(vv.y);
                d[2] = (short)f2bf(vv.z); d[3] = (short)f2bf(vv.w);
            }
        }
        __syncthreads();
        {
            int chunk = t & 7, cl2 = t >> 3;
            #pragma unroll
            for (int rd = 0; rd < 2; ++rd) {
                int c_local = rd * 32 + cl2;
                int c = c0 + c_local;
                unsigned s8[8];
                #pragma unroll
                for (int j = 0; j < 8; ++j)
                    s8[j] = (unsigned)(unsigned short)tile[(chunk * 8 + j) * 68 + c_local];
                uint4 pk;
                pk.x = s8[0] | (s8[1] << 16);
                pk.y = s8[2] | (s8[3] << 16);
                pk.z = s8[4] | (s8[5] << 16);
                pk.w = s8[6] | (s8[7] << 16);
                *(uint4*)&wt[(size_t)c * KTOT + k0 + ((chunk ^ (c & 7)) * 8)] = pk;
            }
        }
    }
}

// ================= bit-sliced CSA unit: 64 neurons x 64 samples, one lane each =========
static __device__ __forceinline__ u64 unit_csa(
    const u64* __restrict__ prow,
    const uint16_t* __restrict__ table_l, const unsigned* __restrict__ bits_l, int n) {
    const uint4* tq = (const uint4*)(table_l + (size_t)n * 32);
    uint4 cwa[4] = {tq[0], tq[1], tq[2], tq[3]};
    uint2 bv = *(const uint2*)(bits_l + (size_t)n * 2);
    unsigned negb = bv.x, valb = bv.y;

    u64 P[4][4];
    #pragma unroll
    for (int k = 0; k < 4; ++k) {
        unsigned w0 = cwa[k].x, w1 = cwa[k].y, w2 = cwa[k].z, w3 = cwa[k].w;
        unsigned cc[8] = { w0 & 0xFFFFu, w0 >> 16, w1 & 0xFFFFu, w1 >> 16,
                           w2 & 0xFFFFu, w2 >> 16, w3 & 0xFFFFu, w3 >> 16 };
        u64 u[8];
        #pragma unroll
        for (int e = 0; e < 8; ++e) {
            int j = (k << 3) + e;
            u64 w = prow[cc[e]];
            u64 negm = 0ull - (u64)((negb >> j) & 1u);
            u64 vm   = 0ull - (u64)((valb >> j) & 1u);
            u[e] = (w ^ negm) & vm;
        }
        u64 s0, c0, s1, c1, s2, c2, b0, c3, t2, d0, b1, d1;
        { u64 t = u[0] ^ u[1]; s0 = t ^ u[2]; c0 = (u[0] & u[1]) | (u[2] & t); }
        { u64 t = u[3] ^ u[4]; s1 = t ^ u[5]; c1 = (u[3] & u[4]) | (u[5] & t); }
        s2 = u[6] ^ u[7]; c2 = u[6] & u[7];
        { u64 t = s0 ^ s1; b0 = t ^ s2; c3 = (s0 & s1) | (s2 & t); }
        { u64 t = c0 ^ c1; t2 = t ^ c2; d0 = (c0 & c1) | (c2 & t); }
        b1 = t2 ^ c3; d1 = t2 & c3;
        P[k][0] = b0; P[k][1] = b1; P[k][2] = d0 ^ d1; P[k][3] = d0 & d1;
    }
    u64 A[5], B[5], U[6];
    { u64 c;
      { u64 t = P[0][0] ^ P[1][0]; A[0] = t; c = P[0][0] & P[1][0]; }
      #pragma unroll
      for (int i = 1; i < 4; ++i) {
          u64 t = P[0][i] ^ P[1][i]; A[i] = t ^ c; c = (P[0][i] & P[1][i]) | (c & t); }
      A[4] = c; }
    { u64 c;
      { u64 t = P[2][0] ^ P[3][0]; B[0] = t; c = P[2][0] & P[3][0]; }
      #pragma unroll
      for (int i = 1; i < 4; ++i) {
          u64 t = P[2][i] ^ P[3][i]; B[i] = t ^ c; c = (P[2][i] & P[3][i]) | (c & t); }
      B[4] = c; }
    { u64 c;
      { u64 t = A[0] ^ B[0]; U[0] = t; c = A[0] & B[0]; }
      #pragma unroll
      for (int i = 1; i < 5; ++i) {
          u64 t = A[i] ^ B[i]; U[i] = t ^ c; c = (A[i] & B[i]) | (c & t); }
      U[5] = c; }
    int K = 60 - __popc(negb & valb);
    u64 c = 0;
    #pragma unroll
    for (int i = 0; i < 6; ++i) {
        u64 ki = 0ull - (u64)((K >> i) & 1);
        u64 t = U[i] ^ ki;
        c = (U[i] & ki) | (c & t);
    }
    return c;
}

// ================= kernel 2: all 3 layers fused, corrected sync mechanics =============
// 512 one-wave zero-LDS blocks (trivially all co-resident; 2 blocks/CU vs >=8 capacity).
// Per-(layer,bg) arrival counter in its OWN 128B line; arrival = one release-RMW by
// lane 0; polling = non-RMW acquire loads (no line dirtying) + s_sleep backoff.
__global__ void __launch_bounds__(64)
k_layers3(const u64* __restrict__ enc2, const uint16_t* __restrict__ table,
          const unsigned* __restrict__ bits, u64* __restrict__ act2,
          int* __restrict__ sync) {
    int unit = blockIdx.x;
    int lane = threadIdx.x;
    int g = unit >> 3, bg = unit & 7;
    int n = (g << 6) + lane;

    // ---- layer 1 ----
    u64 c = unit_csa(enc2 + (size_t)bg * ENC, table, bits, n);
    act2[(size_t)bg * HID + n] = c;
    if (lane == 0)
        __hip_atomic_fetch_add(&sync[bg * 32], 1, __ATOMIC_RELEASE,
                               __HIP_MEMORY_SCOPE_AGENT);
    while (__hip_atomic_load(&sync[bg * 32], __ATOMIC_ACQUIRE,
                             __HIP_MEMORY_SCOPE_AGENT) < 64)
        __builtin_amdgcn_s_sleep(8);

    // ---- layer 2 ----
    c = unit_csa(act2 + (size_t)bg * HID, table + (size_t)HID * 32,
                 bits + (size_t)HID * 2, n);
    act2[(size_t)(8 + bg) * HID + n] = c;
    if (lane == 0)
        __hip_atomic_fetch_add(&sync[(8 + bg) * 32], 1, __ATOMIC_RELEASE,
                               __HIP_MEMORY_SCOPE_AGENT);
    while (__hip_atomic_load(&sync[(8 + bg) * 32], __ATOMIC_ACQUIRE,
                             __HIP_MEMORY_SCOPE_AGENT) < 64)
        __builtin_amdgcn_s_sleep(8);

    // ---- layer 3 ----
    c = unit_csa(act2 + (size_t)(8 + bg) * HID, table + (size_t)2 * HID * 32,
                 bits + (size_t)2 * HID * 2, n);
    act2[(size_t)(16 + bg) * HID + n] = c;
}

// ================= kernel 3: GEMM, 2-phase pipelined, M-tile=64, XCD-pinned nt ========
// grid 1024 = 8 nt x 16 ks x 8 mt. Per step: issue next stage, MFMA current, one
// barrier. 48KB LDS -> 3 blocks/CU, 12 waves/CU.
__global__ void __launch_bounds__(256)
k_gemm_atomic(const u64* __restrict__ act2, const short* __restrict__ wt,
              float* __restrict__ out) {
    __shared__ __attribute__((aligned(16))) short As[2][64 * 64];
    __shared__ __attribute__((aligned(16))) short Bs[2][128 * 64];
    int bid = blockIdx.x;
    int nt = bid & 7, ks = (bid >> 3) & 15, mt = bid >> 7;
    int tid = threadIdx.x, lane = tid & 63;
    int wv = tid >> 6;
    int quad = lane >> 4, cl = lane & 15;
    f32x4 acc[4][2] = {};
    const char* Bb = (const char*)(wt + (size_t)nt * 128 * KTOT + ks * KSPLIT);
    int r = tid >> 3, sub = tid & 7, gg = tid & 7;
    u64 aw[8];

    auto STAGE_B = [&](int kk, int buf) {
        #pragma unroll
        for (int rd = 0; rd < 4; ++rd) {
            size_t go = (size_t)(r + rd * 32) * (KTOT * 2) + kk * 2 + sub * 16;
            gld16(Bb + go, &Bs[buf][(tid + rd * 256) * 8]);
        }
    };
    auto LOAD_A = [&](int kk) {
        int kabs = ks * KSPLIT + kk;
        int l = kabs >> 12, nk = kabs & 4095;
        const u64* base = act2 + ((size_t)(l * 8 + mt)) * HID + nk + gg * 8;
        #pragma unroll
        for (int j = 0; j < 8; ++j) aw[j] = base[j];
    };
    auto PACK_A = [&](int buf) {
        #pragma unroll
        for (int i = 0; i < 2; ++i) {
            int rr = i * 32 + (tid >> 3);
            unsigned sh[8];
            #pragma unroll
            for (int j = 0; j < 8; ++j)
                sh[j] = (unsigned)((aw[j] >> rr) & 1ull) * 0x3F80u;
            uint4 pk;
            pk.x = sh[0] | (sh[1] << 16);
            pk.y = sh[2] | (sh[3] << 16);
            pk.z = sh[4] | (sh[5] << 16);
            pk.w = sh[6] | (sh[7] << 16);
            *(uint4*)&As[buf][rr * 64 + ((gg ^ (rr & 7)) * 8)] = pk;
        }
    };

    // prologue: stage tile 0
    STAGE_B(0, 0);
    LOAD_A(0);
    PACK_A(0);              // compiler inserts vmcnt wait for aw uses
    __syncthreads();        // drains gld16 (vmcnt 0) + ds_writes

    int cur = 0;
    for (int kk = 0; kk < KSPLIT; kk += 64) {
        int nxt = kk + 64;
        if (nxt < KSPLIT) {                 // issue next-tile staging BEFORE compute
            STAGE_B(nxt, cur ^ 1);
            LOAD_A(nxt);
        }
        #pragma unroll
        for (int s = 0; s < 2; ++s) {       // MFMA on current tile (hides staging)
            int xr = ((s * 4 + quad) ^ (cl & 7)) * 8;
            bf16x8 af[4], bfr[2];
            #pragma unroll
            for (int mf = 0; mf < 4; ++mf)
                af[mf] = *(const bf16x8*)&As[cur][(mf * 16 + cl) * 64 + xr];
            #pragma unroll
            for (int nf = 0; nf < 2; ++nf)
                bfr[nf] = *(const bf16x8*)&Bs[cur][(wv * 32 + nf * 16 + cl) * 64 + xr];
            #pragma unroll
            for (int mf = 0; mf < 4; ++mf)
                #pragma unroll
                for (int nf = 0; nf < 2; ++nf)
                    acc[mf][nf] = __builtin_amdgcn_mfma_f32_16x16x32_bf16(
                        af[mf], bfr[nf], acc[mf][nf], 0, 0, 0);
        }
        if (nxt < KSPLIT) PACK_A(cur ^ 1);  // aw ready (compiler-inserted vmcnt)
        __syncthreads();                    // one barrier per K-step
        cur ^= 1;
    }

    #pragma unroll
    for (int mf = 0; mf < 4; ++mf)
        #pragma unroll
        for (int nf = 0; nf < 2; ++nf) {
            int cp = nt * 128 + wv * 32 + nf * 16 + cl;
            if (cp < CLS) {
                #pragma unroll
                for (int rr = 0; rr < 4; ++rr) {
                    int mg = mt * 64 + mf * 16 + quad * 4 + rr;
                    atomicAdd(&out[(size_t)mg * CLS + cp], acc[mf][nf][rr]);
                }
            }
        }
}

extern "C" void kernel_launch(void* const* d_in, const int* in_sizes, int n_in,
                              void* d_out, int out_size, void* d_ws, size_t ws_size,
                              hipStream_t stream) {
    const float* x     = (const float*)d_in[0];
    const float* W0    = (const float*)d_in[1];
    const float* W1    = (const float*)d_in[2];
    const float* W2    = (const float*)d_in[3];
    const float* out_w = (const float*)d_in[4];
    float* out = (float*)d_out;
    char* ws = (char*)d_ws;

    u64*       enc2   = (u64*)(ws + OFF_ENC2);
    u64*       act2   = (u64*)(ws + OFF_ACT2);
    uint16_t*  table  = (uint16_t*)(ws + OFF_TABLE);
    unsigned*  bits   = (unsigned*)(ws + OFF_SGN);
    int*       sync   = (int*)(ws + OFF_CNT);
    short*     wt     = (short*)(ws + OFF_WT);

    hipLaunchKernelGGL(k_prep, dim3(6656), dim3(256), 0, stream,
                       x, enc2, W0, W1, W2, table, bits, out_w, wt, out, sync);
    hipLaunchKernelGGL(k_layers3, dim3(512), dim3(64), 0, stream,
                       enc2, table, bits, act2, sync);
    hipLaunchKernelGGL(k_gemm_atomic, dim3(1024), dim3(256), 0, stream,
                       act2, wt, out);
}

// Round 8
// 279.739 us; speedup vs baseline: 1.0799x; 1.0799x over previous
//
#include <hip/hip_runtime.h>
#include <stdint.h>

typedef unsigned long long u64;
typedef __attribute__((ext_vector_type(8))) short bf16x8;
typedef __attribute__((ext_vector_type(4))) float f32x4;
typedef __attribute__((ext_vector_type(4))) unsigned u32x4;

#define BATCH 512
#define FEAT 256
#define ENC 2048
#define HID 4096
#define CLS 1000
#define KTOT 12288      // 3 * 4096
#define KSPLIT 768

// ws offsets
#define OFF_ENC2   0
#define OFF_ACT2   131072
#define OFF_TABLE  917504
#define OFF_SGN    1703936      // {negbits,validbits} u32 pairs per neuron
#define OFF_WT     2097152

// ---------- fp32 -> bf16 RNE ----------
static __device__ inline unsigned short f2bf(float f) {
    unsigned u = __float_as_uint(f);
    return (unsigned short)((u + 0x7FFFu + ((u >> 16) & 1u)) >> 16);
}

// ================= kernel 1: fused prep = encode+zero | scan | twt =================
// blocks [0,512): encode + zero out   [512,3584): scan (1 wave = 1 row)   [3584,6656): twt
__global__ void __launch_bounds__(256)
k_prep(const float* __restrict__ x, u64* __restrict__ enc2,
       const float* __restrict__ W0, const float* __restrict__ W1,
       const float* __restrict__ W2,
       uint16_t* __restrict__ table, unsigned* __restrict__ bits,
       const float* __restrict__ out_w, short* __restrict__ wt,
       float* __restrict__ out) {
    __shared__ short tile[64 * 68];
    int bid = blockIdx.x;
    int t = threadIdx.x;
    int lane = t & 63;
    int wv = t >> 6;

    if (bid < 512) {
        // zero out (512*256 float4 slots cover the 128000 needed)
        int oidx = bid * 256 + t;
        if (oidx < (BATCH * CLS) / 4) {
            f32x4 z = {0.f, 0.f, 0.f, 0.f};
            *(f32x4*)&out[(size_t)oidx * 4] = z;
        }
        int wid = bid * 4 + wv;
        int f = wid >> 3, bg = wid & 7;
        float v = x[(size_t)(bg * 64 + lane) * FEAT + f];
        v = fminf(fmaxf(v, 0.0f), 1.0f);
        int lev = (int)rintf(v * 255.0f);                // RNE == jnp.round
        unsigned gray = (unsigned)(lev ^ (lev >> 1));
        u64 w = 0;
        #pragma unroll
        for (int bit = 0; bit < 8; ++bit) {
            u64 m = __ballot((gray >> bit) & 1u);
            if (lane == bit) w = m;
        }
        if (lane < 8) enc2[(size_t)bg * ENC + f * 8 + lane] = w;
        return;
    }
    if (bid < 3584) {
        // ---- scan: 1 wave = 1 weight row; ballot+prefix slot assignment (no atomics) --
        int row = (bid - 512) * 4 + wv;
        const float* Wr; int npass;
        if (row < HID)          { Wr = W0 + (size_t)row * ENC;             npass = 1; }
        else if (row < 2 * HID) { Wr = W1 + (size_t)(row - HID) * HID;     npass = 2; }
        else                    { Wr = W2 + (size_t)(row - 2 * HID) * HID; npass = 2; }
        uint16_t* te = table + (size_t)row * 32;
        unsigned cnt = 0, mynegs = 0;
        u64 ltmask = (1ull << lane) - 1ull;
        for (int p = 0; p < npass; ++p) {
            const u32x4* p4 = (const u32x4*)Wr + p * 512 + lane;
            u32x4 v[8];
            #pragma unroll
            for (int j = 0; j < 8; ++j) v[j] = __builtin_nontemporal_load(p4 + j * 64);
            #pragma unroll
            for (int j = 0; j < 8; ++j) {
                int col0 = (p * 8 + j) * 256 + lane * 4;
                unsigned aa[4] = {v[j].x, v[j].y, v[j].z, v[j].w};
                #pragma unroll
                for (int c = 0; c < 4; ++c) {
                    unsigned a = aa[c];
                    u64 m = __ballot(a != 0u);
                    if (a) {
                        int slot = (int)cnt + (int)__popcll(m & ltmask);
                        te[slot] = (uint16_t)(col0 + c);
                        if (a >> 31) mynegs |= 1u << slot;
                    }
                    cnt += (unsigned)__popcll(m);
                }
            }
        }
        // wave OR-reduce of negbits
        #pragma unroll
        for (int off = 32; off; off >>= 1) mynegs |= __shfl_xor(mynegs, off);
        // tail-pad unused slots (disjoint addresses from the scatter -> no ordering hazard)
        if (lane >= (int)cnt && lane < 32) te[lane] = 0;
        if (lane == 0) {
            uint2 pr;
            pr.x = mynegs;
            pr.y = (cnt >= 32) ? 0xFFFFFFFFu : ((1u << cnt) - 1u);
            *(uint2*)(bits + (size_t)row * 2) = pr;
        }
        return;
    }
    {
        // ---- twt: transpose+convert out_w -> wt bf16 (LINEAR [c][k] layout) ----
        int b2 = bid - 3584;
        int kt = b2 % 192, ct = b2 / 192;
        int k0 = kt * 64, c0 = ct * 64;
        {
            int rrow = t >> 4, c4 = t & 15;
            int c = c0 + c4 * 4;
            #pragma unroll
            for (int rd = 0; rd < 4; ++rd) {
                int kl = rd * 16 + rrow;
                f32x4 vv;
                if (c < CLS)
                    vv = __builtin_nontemporal_load(
                        (const f32x4*)&out_w[(size_t)(k0 + kl) * CLS + c]);
                else { vv.x = 0.0f; vv.y = 0.0f; vv.z = 0.0f; vv.w = 0.0f; }
                short* d = &tile[kl * 68 + c4 * 4];
                d[0] = (short)f2bf(vv.x); d[1] = (short)f2bf(vv.y);
                d[2] = (short)f2bf(vv.z); d[3] = (short)f2bf(vv.w);
            }
        }
        __syncthreads();
        {
            int chunk = t & 7, cl2 = t >> 3;
            #pragma unroll
            for (int rd = 0; rd < 2; ++rd) {
                int c_local = rd * 32 + cl2;
                int c = c0 + c_local;
                unsigned s8[8];
                #pragma unroll
                for (int j = 0; j < 8; ++j)
                    s8[j] = (unsigned)(unsigned short)tile[(chunk * 8 + j) * 68 + c_local];
                uint4 pk;
                pk.x = s8[0] | (s8[1] << 16);
                pk.y = s8[2] | (s8[3] << 16);
                pk.z = s8[4] | (s8[5] << 16);
                pk.w = s8[6] | (s8[7] << 16);
                *(uint4*)&wt[(size_t)c * KTOT + k0 + chunk * 8] = pk;
            }
        }
    }
}

// ================= bit-sliced CSA unit: 64 neurons x 64 samples, one lane each =========
static __device__ __forceinline__ u64 unit_csa(
    const u64* __restrict__ prow,
    const uint16_t* __restrict__ table_l, const unsigned* __restrict__ bits_l, int n) {
    const uint4* tq = (const uint4*)(table_l + (size_t)n * 32);
    uint4 cwa[4] = {tq[0], tq[1], tq[2], tq[3]};
    uint2 bv = *(const uint2*)(bits_l + (size_t)n * 2);
    unsigned negb = bv.x, valb = bv.y;

    u64 P[4][4];
    #pragma unroll
    for (int k = 0; k < 4; ++k) {
        unsigned w0 = cwa[k].x, w1 = cwa[k].y, w2 = cwa[k].z, w3 = cwa[k].w;
        unsigned cc[8] = { w0 & 0xFFFFu, w0 >> 16, w1 & 0xFFFFu, w1 >> 16,
                           w2 & 0xFFFFu, w2 >> 16, w3 & 0xFFFFu, w3 >> 16 };
        u64 u[8];
        #pragma unroll
        for (int e = 0; e < 8; ++e) {
            int j = (k << 3) + e;
            u64 w = prow[cc[e]];
            u64 negm = 0ull - (u64)((negb >> j) & 1u);
            u64 vm   = 0ull - (u64)((valb >> j) & 1u);
            u[e] = (w ^ negm) & vm;
        }
        u64 s0, c0, s1, c1, s2, c2, b0, c3, t2, d0, b1, d1;
        { u64 t = u[0] ^ u[1]; s0 = t ^ u[2]; c0 = (u[0] & u[1]) | (u[2] & t); }
        { u64 t = u[3] ^ u[4]; s1 = t ^ u[5]; c1 = (u[3] & u[4]) | (u[5] & t); }
        s2 = u[6] ^ u[7]; c2 = u[6] & u[7];
        { u64 t = s0 ^ s1; b0 = t ^ s2; c3 = (s0 & s1) | (s2 & t); }
        { u64 t = c0 ^ c1; t2 = t ^ c2; d0 = (c0 & c1) | (c2 & t); }
        b1 = t2 ^ c3; d1 = t2 & c3;
        P[k][0] = b0; P[k][1] = b1; P[k][2] = d0 ^ d1; P[k][3] = d0 & d1;
    }
    u64 A[5], B[5], U[6];
    { u64 c;
      { u64 t = P[0][0] ^ P[1][0]; A[0] = t; c = P[0][0] & P[1][0]; }
      #pragma unroll
      for (int i = 1; i < 4; ++i) {
          u64 t = P[0][i] ^ P[1][i]; A[i] = t ^ c; c = (P[0][i] & P[1][i]) | (c & t); }
      A[4] = c; }
    { u64 c;
      { u64 t = P[2][0] ^ P[3][0]; B[0] = t; c = P[2][0] & P[3][0]; }
      #pragma unroll
      for (int i = 1; i < 4; ++i) {
          u64 t = P[2][i] ^ P[3][i]; B[i] = t ^ c; c = (P[2][i] & P[3][i]) | (c & t); }
      B[4] = c; }
    { u64 c;
      { u64 t = A[0] ^ B[0]; U[0] = t; c = A[0] & B[0]; }
      #pragma unroll
      for (int i = 1; i < 5; ++i) {
          u64 t = A[i] ^ B[i]; U[i] = t ^ c; c = (A[i] & B[i]) | (c & t); }
      U[5] = c; }
    int K = 60 - __popc(negb & valb);
    u64 c = 0;
    #pragma unroll
    for (int i = 0; i < 6; ++i) {
        u64 ki = 0ull - (u64)((K >> i) & 1);
        u64 t = U[i] ^ ki;
        c = (U[i] & ki) | (c & t);
    }
    return c;
}

// ================= kernel 2: bit-sliced layer (R1/R5-proven: 512 x 64) =================
__global__ void __launch_bounds__(64)
k_layer(const u64* __restrict__ prev2, int Kwords,
        const uint16_t* __restrict__ table_l, const unsigned* __restrict__ bits_l,
        u64* __restrict__ actout) {
    int unit = blockIdx.x;
    int lane = threadIdx.x;
    int g = unit >> 3, bg = unit & 7;
    int n = (g << 6) + lane;
    u64 c = unit_csa(prev2 + (size_t)bg * Kwords, table_l, bits_l, n);
    actout[(size_t)bg * HID + n] = c;
}

// ================= kernel 3: GEMM, zero-LDS direct fragment loads =====================
// grid 1024 = 8 nt x 16 ks x 8 mt (nt=bid&7 -> wt panel XCD-pinned, L2-resident).
// No LDS, no barriers: A expanded bit->bf16 in-register per K32 slice; B fragments
// loaded straight from linear wt. Pure load/VALU/MFMA dataflow; 16 waves/CU.
__global__ void __launch_bounds__(256)
k_gemm_direct(const u64* __restrict__ act2, const short* __restrict__ wt,
              float* __restrict__ out) {
    int bid = blockIdx.x;
    int nt = bid & 7, ks = (bid >> 3) & 15, mt = bid >> 7;
    int tid = threadIdx.x, lane = tid & 63;
    int wv = tid >> 6;
    int quad = lane >> 4, cl = lane & 15;
    f32x4 acc[4][2] = {};
    const short* Bc0 = wt + (size_t)(nt * 128 + wv * 32 + cl) * KTOT;   // nf = 0 column
    const short* Bc1 = Bc0 + (size_t)16 * KTOT;                          // nf = 1 column
    const u64*   Arow = act2 + (size_t)mt * HID;                         // + l*8*HID per l
    int kbase = ks * KSPLIT;

    #pragma unroll 2
    for (int t32 = 0; t32 < KSPLIT / 32; ++t32) {
        int kabs = kbase + t32 * 32;
        int l = kabs >> 12, nk = kabs & 4095;
        const u64* aw = Arow + (size_t)l * (8 * HID) + nk + quad * 8;
        u64 w[8];
        #pragma unroll
        for (int j = 0; j < 8; ++j) w[j] = aw[j];
        bf16x8 bfr0 = *(const bf16x8*)&Bc0[kabs + quad * 8];
        bf16x8 bfr1 = *(const bf16x8*)&Bc1[kabs + quad * 8];
        // shift each word by cl: bit (mf*16) of (lo,hi) selects fragment rows
        unsigned tl[8], th[8];
        #pragma unroll
        for (int j = 0; j < 8; ++j) {
            u64 t = w[j] >> cl;
            tl[j] = (unsigned)t;
            th[j] = (unsigned)(t >> 32);
        }
        bf16x8 af[4];
        #pragma unroll
        for (int mf = 0; mf < 4; ++mf) {
            unsigned sh = (mf & 1) * 16;
            uint4 pk;
            if (mf < 2) {
                pk.x = (((tl[0] >> sh) & 1u) | (((tl[1] >> sh) & 1u) << 16)) * 0x3F80u;
                pk.y = (((tl[2] >> sh) & 1u) | (((tl[3] >> sh) & 1u) << 16)) * 0x3F80u;
                pk.z = (((tl[4] >> sh) & 1u) | (((tl[5] >> sh) & 1u) << 16)) * 0x3F80u;
                pk.w = (((tl[6] >> sh) & 1u) | (((tl[7] >> sh) & 1u) << 16)) * 0x3F80u;
            } else {
                pk.x = (((th[0] >> sh) & 1u) | (((th[1] >> sh) & 1u) << 16)) * 0x3F80u;
                pk.y = (((th[2] >> sh) & 1u) | (((th[3] >> sh) & 1u) << 16)) * 0x3F80u;
                pk.z = (((th[4] >> sh) & 1u) | (((th[5] >> sh) & 1u) << 16)) * 0x3F80u;
                pk.w = (((th[6] >> sh) & 1u) | (((th[7] >> sh) & 1u) << 16)) * 0x3F80u;
            }
            af[mf] = *(bf16x8*)&pk;
        }
        #pragma unroll
        for (int mf = 0; mf < 4; ++mf) {
            acc[mf][0] = __builtin_amdgcn_mfma_f32_16x16x32_bf16(af[mf], bfr0,
                                                                acc[mf][0], 0, 0, 0);
            acc[mf][1] = __builtin_amdgcn_mfma_f32_16x16x32_bf16(af[mf], bfr1,
                                                                acc[mf][1], 0, 0, 0);
        }
    }

    #pragma unroll
    for (int mf = 0; mf < 4; ++mf)
        #pragma unroll
        for (int nf = 0; nf < 2; ++nf) {
            int cp = nt * 128 + wv * 32 + nf * 16 + cl;
            if (cp < CLS) {
                #pragma unroll
                for (int rr = 0; rr < 4; ++rr) {
                    int mg = mt * 64 + mf * 16 + quad * 4 + rr;
                    atomicAdd(&out[(size_t)mg * CLS + cp], acc[mf][nf][rr]);
                }
            }
        }
}

extern "C" void kernel_launch(void* const* d_in, const int* in_sizes, int n_in,
                              void* d_out, int out_size, void* d_ws, size_t ws_size,
                              hipStream_t stream) {
    const float* x     = (const float*)d_in[0];
    const float* W0    = (const float*)d_in[1];
    const float* W1    = (const float*)d_in[2];
    const float* W2    = (const float*)d_in[3];
    const float* out_w = (const float*)d_in[4];
    float* out = (float*)d_out;
    char* ws = (char*)d_ws;

    u64*       enc2   = (u64*)(ws + OFF_ENC2);
    u64*       act2   = (u64*)(ws + OFF_ACT2);
    uint16_t*  table  = (uint16_t*)(ws + OFF_TABLE);
    unsigned*  bits   = (unsigned*)(ws + OFF_SGN);
    short*     wt     = (short*)(ws + OFF_WT);

    hipLaunchKernelGGL(k_prep, dim3(6656), dim3(256), 0, stream,
                       x, enc2, W0, W1, W2, table, bits, out_w, wt, out);
    hipLaunchKernelGGL(k_layer, dim3(512), dim3(64), 0, stream,
                       enc2, ENC, table, bits, act2);
    hipLaunchKernelGGL(k_layer, dim3(512), dim3(64), 0, stream,
                       act2, HID, table + (size_t)HID * 32, bits + (size_t)HID * 2,
                       act2 + 8 * HID);
    hipLaunchKernelGGL(k_layer, dim3(512), dim3(64), 0, stream,
                       act2 + 8 * HID, HID, table + (size_t)2 * HID * 32,
                       bits + (size_t)2 * HID * 2, act2 + 16 * HID);
    hipLaunchKernelGGL(k_gemm_direct, dim3(1024), dim3(256), 0, stream,
                       act2, wt, out);
}